// Round 1
// baseline (4021.483 us; speedup 1.0000x reference)
//
#include <hip/hip_runtime.h>
#include <cstdint>

#define T_DIM 512
#define B_DIM 256
#define F_DIM 513
#define DX    256
#define H_DIM 128
#define G4    512
#define Z_DIM 16
#define ZG_D  32
#define DZX_D 128
#define M_ROWS (B_DIM * T_DIM)   // 131072

__device__ __forceinline__ float fast_tanh(float x) {
    return 1.0f - 2.0f / (__expf(2.0f * x) + 1.0f);
}
__device__ __forceinline__ float fast_sig(float x) {
    return 1.0f / (1.0f + __expf(-x));
}

__global__ void bias_comb_kernel(const float* __restrict__ a,
                                 const float* __restrict__ b,
                                 float* __restrict__ c) {
    int i = threadIdx.x;
    if (i < G4) c[i] = a[i] + b[i];
}

// Generic tiled fp32 GEMM:  C[m,n] = act(sum_k A[m,k] * W[n,k] + bias[n])
// 128x128 tile, 256 threads, 8x8 per thread (round-3: was 64x64/4x4 — FMA:LDS
// issue ratio 64:~48 per kk vs old 16:24).
// ACT: 0 none, 1 tanh, 2 exp
// AMODE: 0 contiguous row-major [M,K] (requires K%16==0), 1 x-gather A[m,k]=x[b,k,t], m=b*T+t
// CMODE: 0 contiguous [M,N] (requires N%128==0), 1 transposed out[b,n,t] with n<N guard
// GUARD: scalar+bounds-guarded W loads (K edge or N edge)
template<int ACT, int AMODE, int CMODE, bool GUARD>
__global__ __launch_bounds__(256, 4) void gemm_kernel(
    const float* __restrict__ A, const float* __restrict__ W,
    const float* __restrict__ bias, float* __restrict__ C,
    int M, int N, int K)
{
    __shared__ float As[16][136];
    __shared__ float Bs[16][136];
    const int tid = threadIdx.x;
    const int m0 = blockIdx.y * 128;
    const int n0 = blockIdx.x * 128;
    const int tm = tid >> 4;   // 0..15
    const int tn = tid & 15;   // 0..15
    float acc[8][8] = {};
    const int kTiles = (K + 15) >> 4;
    for (int kt = 0; kt < kTiles; ++kt) {
        const int k0 = kt << 4;
        // ---- load A tile (transposed into LDS: As[k][m]) ----
        if (AMODE == 0) {
            const int m  = tid >> 1;        // 0..127
            const int kh = tid & 1;         // 0..1
            const float* ap = &A[(size_t)(m0 + m) * K + k0 + kh * 8];
            const float4 v0 = *(const float4*)(ap);
            const float4 v1 = *(const float4*)(ap + 4);
            As[kh * 8 + 0][m] = v0.x; As[kh * 8 + 1][m] = v0.y;
            As[kh * 8 + 2][m] = v0.z; As[kh * 8 + 3][m] = v0.w;
            As[kh * 8 + 4][m] = v1.x; As[kh * 8 + 5][m] = v1.y;
            As[kh * 8 + 6][m] = v1.z; As[kh * 8 + 7][m] = v1.w;
        } else {
            const int m  = tid & 127;       // lane-consecutive m -> t-contiguous, coalesced
            const int kh = tid >> 7;        // 0..1
            const int mg = m0 + m;
            const int bb = mg >> 9;         // /T
            const int tt = mg & 511;        // %T
            const size_t base = (size_t)bb * (F_DIM * T_DIM) + tt;
            #pragma unroll
            for (int j = 0; j < 8; ++j) {
                const int k = k0 + kh * 8 + j;
                As[kh * 8 + j][m] = (k < K) ? A[base + (size_t)k * T_DIM] : 0.0f;
            }
        }
        // ---- load W tile (Bs[k][n]) ----
        {
            const int n  = tid >> 1;        // 0..127
            const int kh = tid & 1;
            const int ng = n0 + n;
            if (!GUARD) {
                const float* wp = &W[(size_t)ng * K + k0 + kh * 8];
                const float4 v0 = *(const float4*)(wp);
                const float4 v1 = *(const float4*)(wp + 4);
                Bs[kh * 8 + 0][n] = v0.x; Bs[kh * 8 + 1][n] = v0.y;
                Bs[kh * 8 + 2][n] = v0.z; Bs[kh * 8 + 3][n] = v0.w;
                Bs[kh * 8 + 4][n] = v1.x; Bs[kh * 8 + 5][n] = v1.y;
                Bs[kh * 8 + 6][n] = v1.z; Bs[kh * 8 + 7][n] = v1.w;
            } else {
                #pragma unroll
                for (int j = 0; j < 8; ++j) {
                    const int k = k0 + kh * 8 + j;
                    float v = 0.0f;
                    if (ng < N && k < K) v = W[(size_t)ng * K + k];
                    Bs[kh * 8 + j][n] = v;
                }
            }
        }
        __syncthreads();
        #pragma unroll
        for (int kk = 0; kk < 16; ++kk) {
            const float4 a0 = *(const float4*)&As[kk][tm * 8];
            const float4 a1 = *(const float4*)&As[kk][tm * 8 + 4];
            const float4 b0 = *(const float4*)&Bs[kk][tn * 8];
            const float4 b1 = *(const float4*)&Bs[kk][tn * 8 + 4];
            const float a[8] = { a0.x, a0.y, a0.z, a0.w, a1.x, a1.y, a1.z, a1.w };
            const float b[8] = { b0.x, b0.y, b0.z, b0.w, b1.x, b1.y, b1.z, b1.w };
            #pragma unroll
            for (int i = 0; i < 8; ++i)
                #pragma unroll
                for (int j = 0; j < 8; ++j)
                    acc[i][j] += a[i] * b[j];
        }
        __syncthreads();
    }
    // ---- epilogue ----
    #pragma unroll
    for (int i = 0; i < 8; ++i) {
        const int m = m0 + tm * 8 + i;
        if (CMODE == 0) {
            float r[8];
            #pragma unroll
            for (int j = 0; j < 8; ++j) {
                const int n = n0 + tn * 8 + j;
                float v = acc[i][j] + bias[n];
                if (ACT == 1) v = fast_tanh(v);
                else if (ACT == 2) v = __expf(v);
                r[j] = v;
            }
            *(float4*)&C[(size_t)m * N + n0 + tn * 8]     = make_float4(r[0], r[1], r[2], r[3]);
            *(float4*)&C[(size_t)m * N + n0 + tn * 8 + 4] = make_float4(r[4], r[5], r[6], r[7]);
        } else {
            const int bb = m >> 9;
            const int tt = m & 511;
            #pragma unroll
            for (int j = 0; j < 8; ++j) {
                const int n = n0 + tn * 8 + j;
                if (n < N) {
                    float v = acc[i][j] + bias[n];
                    if (ACT == 1) v = fast_tanh(v);
                    else if (ACT == 2) v = __expf(v);
                    C[(size_t)bb * (F_DIM * T_DIM) + (size_t)n * T_DIM + tt] = v;
                }
            }
        }
    }
}

#define PIN4(v) asm volatile("" : "+v"((v).x), "+v"((v).y), "+v"((v).z), "+v"((v).w))

// Backward LSTM: one block per batch row b, 512 threads (8 waves).
// Thread (wave w, lane l): h-index j = w*16 + (l&15), K-quarter kq = l>>4.
// Per-thread weights: 4 gates x 32 K-elems = 128 VGPRs.
// Round-3 fix: VGPR_Count was 84 — the single pre-loop PIN did NOT keep the
// weights resident; compiler re-materialized them every t step (~5x VALU
// surplus at 77% VALUBusy). Re-PIN all 32 float4 at the BOTTOM of every
// iteration -> loop-carried asm dependence forces them to live in VGPRs
// across the back-edge. Budget ~170 < 256 cap (launch_bounds(512,2)).
// Cross-kq combine: shfl_xor 16 + 32 (in-wave). Double-buffered LDS h, ONE
// barrier per step. gin layout [B,T,512] (biases folded), g_out [B,T,128].
__global__ __launch_bounds__(512, 2) void lstm_kernel(
    const float* __restrict__ gin,
    const float* __restrict__ W_hh,   // [512,128] row-major
    float* __restrict__ g_out)
{
    __shared__ float hbuf[2][128];
    const int tid  = threadIdx.x;
    const int b    = blockIdx.x;
    const int lane = tid & 63;
    const int w    = tid >> 6;             // wave 0..7
    const int j    = w * 16 + (lane & 15); // h index 0..127
    const int kq   = lane >> 4;            // K-quarter 0..3

    // weights: rows j, j+128, j+256, j+384, float4 cols [kq*8, kq*8+8)
    float4 wi[8], wf[8], wg[8], wo[8];
    {
        const float4* w4 = (const float4*)W_hh;
        const int cb = kq * 8;
        #pragma unroll
        for (int q = 0; q < 8; ++q) {
            wi[q] = w4[(size_t)(j      ) * 32 + cb + q];
            wf[q] = w4[(size_t)(j + 128) * 32 + cb + q];
            wg[q] = w4[(size_t)(j + 256) * 32 + cb + q];
            wo[q] = w4[(size_t)(j + 384) * 32 + cb + q];
        }
        #pragma unroll
        for (int q = 0; q < 8; ++q) { PIN4(wi[q]); PIN4(wf[q]); PIN4(wg[q]); PIN4(wo[q]); }
    }
    if (tid < 128) { hbuf[0][tid] = 0.f; hbuf[1][tid] = 0.f; }
    float c = 0.0f;
    __syncthreads();

    const float* ginb = gin + (size_t)b * T_DIM * G4;
    float gi = ginb[(size_t)(T_DIM - 1) * G4 + j];
    float gf = ginb[(size_t)(T_DIM - 1) * G4 + j + 128];
    float gg = ginb[(size_t)(T_DIM - 1) * G4 + j + 256];
    float go = ginb[(size_t)(T_DIM - 1) * G4 + j + 384];

    int buf = 0;
    for (int t = T_DIM - 1; t >= 0; --t) {
        float ngi = 0.f, ngf = 0.f, ngg = 0.f, ngo = 0.f;
        if (t > 0) {
            const size_t base = (size_t)(t - 1) * G4;
            ngi = ginb[base + j];
            ngf = ginb[base + j + 128];
            ngg = ginb[base + j + 256];
            ngo = ginb[base + j + 384];
        }
        float si = 0.f, sf = 0.f, sg = 0.f, so = 0.f;
        {
            const float4* h4 = (const float4*)&hbuf[buf][kq * 32];
            #pragma unroll
            for (int q = 0; q < 8; ++q) {
                const float4 hv = h4[q];
                si += wi[q].x * hv.x + wi[q].y * hv.y + wi[q].z * hv.z + wi[q].w * hv.w;
                sf += wf[q].x * hv.x + wf[q].y * hv.y + wf[q].z * hv.z + wf[q].w * hv.w;
                sg += wg[q].x * hv.x + wg[q].y * hv.y + wg[q].z * hv.z + wg[q].w * hv.w;
                so += wo[q].x * hv.x + wo[q].y * hv.y + wo[q].z * hv.z + wo[q].w * hv.w;
            }
        }
        si += __shfl_xor(si, 16, 64); si += __shfl_xor(si, 32, 64);
        sf += __shfl_xor(sf, 16, 64); sf += __shfl_xor(sf, 32, 64);
        sg += __shfl_xor(sg, 16, 64); sg += __shfl_xor(sg, 32, 64);
        so += __shfl_xor(so, 16, 64); so += __shfl_xor(so, 32, 64);
        si += gi; sf += gf; sg += gg; so += go;
        c = fast_sig(sf) * c + fast_sig(si) * fast_tanh(sg);
        const float h = fast_sig(so) * fast_tanh(c);
        buf ^= 1;
        if (kq == 0) {
            hbuf[buf][j] = h;
            g_out[((size_t)b * T_DIM + t) * H_DIM + j] = h;
        }
        __syncthreads();
        gi = ngi; gf = ngf; gg = ngg; go = ngo;
        // Loop-carried pin: weights must cross the back-edge in VGPRs.
        #pragma unroll
        for (int q = 0; q < 8; ++q) { PIN4(wi[q]); PIN4(wf[q]); PIN4(wg[q]); PIN4(wo[q]); }
    }
}

// Inference scan: one block (1 wave, 64 lanes) per batch row. All weights in registers.
// g layout [B,T,128], eps layout [T,B,16], z_out layout [B,T,16].
__global__ __launch_bounds__(64, 1) void infer_kernel(
    const float* __restrict__ g,
    const float* __restrict__ eps,
    const float* __restrict__ W_zg0, const float* __restrict__ b_zg0,
    const float* __restrict__ W_zg1, const float* __restrict__ b_zg1,
    const float* __restrict__ W_im,  const float* __restrict__ b_im,
    const float* __restrict__ W_il,  const float* __restrict__ b_il,
    float* __restrict__ z_out)
{
    __shared__ float zbuf[16];
    __shared__ float hzbuf[32];
    __shared__ float h2buf[128];
    const int l = threadIdx.x;
    const int b = blockIdx.x;

    // stage-1 weights: W_zg0 row (l&31), 16 wide
    const int r0 = l & 31;
    float4 wz0[4];
    #pragma unroll
    for (int q = 0; q < 4; ++q) wz0[q] = ((const float4*)W_zg0)[r0 * 4 + q];
    const float bz0 = b_zg0[r0];
    // stage-2 weights: W_zg1 rows l and l+64, 32 wide each
    float4 w1a[8], w1b[8];
    #pragma unroll
    for (int q = 0; q < 8; ++q) {
        w1a[q] = ((const float4*)W_zg1)[l * 8 + q];
        w1b[q] = ((const float4*)W_zg1)[(l + 64) * 8 + q];
    }
    const float bz1a = b_zg1[l], bz1b = b_zg1[l + 64];
    // stage-3 weights: output o=l&31 (o<16: zm row o; else zl row o-16), k half = l>>5
    const int o = l & 31;
    const int half = l >> 5;
    const float* w3p = (o < 16) ? (W_im + o * 128) : (W_il + (o - 16) * 128);
    float4 w3[16];
    #pragma unroll
    for (int q = 0; q < 16; ++q) w3[q] = ((const float4*)(w3p + half * 64))[q];
    const float b3 = (o < 16) ? b_im[o] : b_il[o - 16];

    if (l < 16) zbuf[l] = 0.0f;
    __syncthreads();

    const float* gb = g + (size_t)b * T_DIM * 128;
    float ngl0 = gb[l];
    float ngl1 = gb[64 + l];
    float neps = (l < 16) ? eps[(size_t)b * 16 + l] : 0.0f;
    for (int t = 0; t < T_DIM; ++t) {
        const float gl0 = ngl0, gl1 = ngl1, epsv = neps;
        if (t + 1 < T_DIM) {
            ngl0 = gb[(size_t)(t + 1) * 128 + l];
            ngl1 = gb[(size_t)(t + 1) * 128 + 64 + l];
            neps = (l < 16) ? eps[((size_t)(t + 1) * B_DIM + b) * 16 + l] : 0.0f;
        }
        // stage 1: hz = tanh(W_zg0 @ z + b_zg0), lanes 0..31
        float s1 = bz0;
        {
            const float4* z4 = (const float4*)zbuf;
            #pragma unroll
            for (int q = 0; q < 4; ++q) {
                const float4 zv = z4[q];
                s1 += wz0[q].x * zv.x + wz0[q].y * zv.y + wz0[q].z * zv.z + wz0[q].w * zv.w;
            }
        }
        const float hz = fast_tanh(s1);
        __syncthreads();
        if (l < 32) hzbuf[l] = hz;
        __syncthreads();
        // stage 2: hz2 = tanh(W_zg1 @ hz + b_zg1); g_t = 0.5*(hz2 + g_rnn)
        float s2a = bz1a, s2b = bz1b;
        {
            const float4* hz4 = (const float4*)hzbuf;
            #pragma unroll
            for (int q = 0; q < 8; ++q) {
                const float4 hv = hz4[q];
                s2a += w1a[q].x * hv.x + w1a[q].y * hv.y + w1a[q].z * hv.z + w1a[q].w * hv.w;
                s2b += w1b[q].x * hv.x + w1b[q].y * hv.y + w1b[q].z * hv.z + w1b[q].w * hv.w;
            }
        }
        const float gt0 = 0.5f * (fast_tanh(s2a) + gl0);
        const float gt1 = 0.5f * (fast_tanh(s2b) + gl1);
        __syncthreads();
        h2buf[l]      = gt0;
        h2buf[l + 64] = gt1;
        __syncthreads();
        // stage 3: zm/zl dot-128, split over lane pairs (l, l^32), outputs o=l&31
        float s3 = 0.0f;
        {
            const float4* h24 = (const float4*)(h2buf + half * 64);
            #pragma unroll
            for (int q = 0; q < 16; ++q) {
                const float4 hv = h24[q];
                s3 += w3[q].x * hv.x + w3[q].y * hv.y + w3[q].z * hv.z + w3[q].w * hv.w;
            }
        }
        const float full = s3 + __shfl_xor(s3, 32, 64);
        const float val = full + b3;                 // o<16: zm[o], o>=16: zl[o-16]
        const float other = __shfl_xor(val, 16, 64); // for l<16: zl[l]
        const float znew = val + epsv * __expf(0.5f * other);
        __syncthreads();
        if (l < 16) {
            zbuf[l] = znew;
            z_out[((size_t)b * T_DIM + t) * 16 + l] = znew;
        }
        __syncthreads();
    }
}

extern "C" void kernel_launch(void* const* d_in, const int* in_sizes, int n_in,
                              void* d_out, int out_size, void* d_ws, size_t ws_size,
                              hipStream_t stream)
{
    const float* x     = (const float*)d_in[0];
    const float* eps   = (const float*)d_in[1];
    const float* W_xg  = (const float*)d_in[2];
    const float* b_xg  = (const float*)d_in[3];
    const float* W_ih  = (const float*)d_in[4];
    const float* W_hh  = (const float*)d_in[5];
    const float* b_ih  = (const float*)d_in[6];
    const float* b_hh  = (const float*)d_in[7];
    const float* W_zg0 = (const float*)d_in[8];
    const float* b_zg0 = (const float*)d_in[9];
    const float* W_zg1 = (const float*)d_in[10];
    const float* b_zg1 = (const float*)d_in[11];
    const float* W_im  = (const float*)d_in[12];
    const float* b_im  = (const float*)d_in[13];
    const float* W_il  = (const float*)d_in[14];
    const float* b_il  = (const float*)d_in[15];
    // 16..27: gate/prop/pm/pl weights — dead code (outputs unused by reference return)
    const float* W_zx0 = (const float*)d_in[28];
    const float* b_zx0 = (const float*)d_in[29];
    const float* W_zx1 = (const float*)d_in[30];
    const float* b_zx1 = (const float*)d_in[31];
    const float* W_gy  = (const float*)d_in[32];
    const float* b_gy  = (const float*)d_in[33];
    float* out = (float*)d_out;
    float* ws  = (float*)d_ws;

    // workspace layout (floats)
    float* xg  = ws;                        // 131072*256 = 33,554,432
    float* gin = ws + 33554432ull;          // 131072*512 = 67,108,864
    float* g   = ws + 100663296ull;         // 131072*128 = 16,777,216
    float* z   = ws + 117440512ull;         // 131072*16  =  2,097,152
    float* bc  = ws + 119537664ull;         // 512
    float* hy1 = ws;                        // alias xg (dead after G2)
    float* hy2 = ws + 16777216ull;          // alias xg upper half

    bias_comb_kernel<<<1, 512, 0, stream>>>(b_ih, b_hh, bc);
    // G1: xg = tanh(xs @ W_xg.T + b_xg), m = b*T+t, A = x gather, K=513
    gemm_kernel<1, 1, 0, true><<<dim3(DX / 128, M_ROWS / 128), 256, 0, stream>>>(
        x, W_xg, b_xg, xg, M_ROWS, DX, F_DIM);
    // G2: gin = xg @ W_ih.T + (b_ih + b_hh), K=256, N=512
    gemm_kernel<0, 0, 0, false><<<dim3(G4 / 128, M_ROWS / 128), 256, 0, stream>>>(
        xg, W_ih, bc, gin, M_ROWS, G4, DX);
    // backward LSTM scan -> g
    lstm_kernel<<<B_DIM, 512, 0, stream>>>(gin, W_hh, g);
    // inference scan -> z
    infer_kernel<<<B_DIM, 64, 0, stream>>>(g, eps, W_zg0, b_zg0, W_zg1, b_zg1,
                                           W_im, b_im, W_il, b_il, z);
    // y path
    gemm_kernel<1, 0, 0, false><<<dim3(DZX_D / 128, M_ROWS / 128), 256, 0, stream>>>(
        z, W_zx0, b_zx0, hy1, M_ROWS, DZX_D, Z_DIM);
    gemm_kernel<1, 0, 0, false><<<dim3(DZX_D / 128, M_ROWS / 128), 256, 0, stream>>>(
        hy1, W_zx1, b_zx1, hy2, M_ROWS, DZX_D, DZX_D);
    gemm_kernel<2, 0, 1, true><<<dim3(5, M_ROWS / 128), 256, 0, stream>>>(
        hy2, W_gy, b_gy, out, M_ROWS, F_DIM, DZX_D);
}

// Round 3
// 3021.180 us; speedup vs baseline: 1.3311x; 1.3311x over previous
//
#include <hip/hip_runtime.h>
#include <cstdint>

#define T_DIM 512
#define B_DIM 256
#define F_DIM 513
#define DX    256
#define H_DIM 128
#define G4    512
#define Z_DIM 16
#define ZG_D  32
#define DZX_D 128
#define M_ROWS (B_DIM * T_DIM)   // 131072

__device__ __forceinline__ float fast_tanh(float x) {
    return 1.0f - 2.0f / (__expf(2.0f * x) + 1.0f);
}
__device__ __forceinline__ float fast_sig(float x) {
    return 1.0f / (1.0f + __expf(-x));
}

__global__ void bias_comb_kernel(const float* __restrict__ a,
                                 const float* __restrict__ b,
                                 float* __restrict__ c) {
    int i = threadIdx.x;
    if (i < G4) c[i] = a[i] + b[i];
}

// Generic tiled fp32 GEMM:  C[m,n] = act(sum_k A[m,k] * W[n,k] + bias[n])
// 128x128 tile, 256 threads, 8x8 per thread in a 2x2-of-4 split layout
// (fragments at tm*4 and tm*4+64 -> 2-way LDS bank aliasing = free, vs 4-way
// for contiguous tn*8).
// Round-4 fix: launch_bounds(256,4) capped VGPRs at 128; allocator picked 64
// and spilled the whole 64-reg accumulator to scratch (WRITE_SIZE 2.4 GB vs
// 268 MB output, VALUBusy 19%). (256,3) caps at 170 — the ~130 needed fit.
// ACT: 0 none, 1 tanh, 2 exp
// AMODE: 0 contiguous row-major [M,K] (requires K%16==0 or K==16), 1 x-gather A[m,k]=x[b,k,t], m=b*T+t
// CMODE: 0 contiguous [M,N] (requires N%128==0), 1 transposed out[b,n,t] with n<N guard
// GUARD: scalar+bounds-guarded W loads (K edge or N edge)
template<int ACT, int AMODE, int CMODE, bool GUARD>
__global__ __launch_bounds__(256, 3) void gemm_kernel(
    const float* __restrict__ A, const float* __restrict__ W,
    const float* __restrict__ bias, float* __restrict__ C,
    int M, int N, int K)
{
    __shared__ float As[16][136];
    __shared__ float Bs[16][136];
    const int tid = threadIdx.x;
    const int m0 = blockIdx.y * 128;
    const int n0 = blockIdx.x * 128;
    const int tm = tid >> 4;   // 0..15
    const int tn = tid & 15;   // 0..15
    float acc[8][8] = {};
    const int kTiles = (K + 15) >> 4;
    for (int kt = 0; kt < kTiles; ++kt) {
        const int k0 = kt << 4;
        // ---- load A tile (transposed into LDS: As[k][m]) ----
        if (AMODE == 0) {
            const int m  = tid >> 1;        // 0..127
            const int kh = tid & 1;         // 0..1
            const float* ap = &A[(size_t)(m0 + m) * K + k0 + kh * 8];
            const float4 v0 = *(const float4*)(ap);
            const float4 v1 = *(const float4*)(ap + 4);
            As[kh * 8 + 0][m] = v0.x; As[kh * 8 + 1][m] = v0.y;
            As[kh * 8 + 2][m] = v0.z; As[kh * 8 + 3][m] = v0.w;
            As[kh * 8 + 4][m] = v1.x; As[kh * 8 + 5][m] = v1.y;
            As[kh * 8 + 6][m] = v1.z; As[kh * 8 + 7][m] = v1.w;
        } else {
            const int m  = tid & 127;       // lane-consecutive m -> t-contiguous, coalesced
            const int kh = tid >> 7;        // 0..1
            const int mg = m0 + m;
            const int bb = mg >> 9;         // /T
            const int tt = mg & 511;        // %T
            const size_t base = (size_t)bb * (F_DIM * T_DIM) + tt;
            #pragma unroll
            for (int j = 0; j < 8; ++j) {
                const int k = k0 + kh * 8 + j;
                As[kh * 8 + j][m] = (k < K) ? A[base + (size_t)k * T_DIM] : 0.0f;
            }
        }
        // ---- load W tile (Bs[k][n]) ----
        {
            const int n  = tid >> 1;        // 0..127
            const int kh = tid & 1;
            const int ng = n0 + n;
            if (!GUARD) {
                const float* wp = &W[(size_t)ng * K + k0 + kh * 8];
                const float4 v0 = *(const float4*)(wp);
                const float4 v1 = *(const float4*)(wp + 4);
                Bs[kh * 8 + 0][n] = v0.x; Bs[kh * 8 + 1][n] = v0.y;
                Bs[kh * 8 + 2][n] = v0.z; Bs[kh * 8 + 3][n] = v0.w;
                Bs[kh * 8 + 4][n] = v1.x; Bs[kh * 8 + 5][n] = v1.y;
                Bs[kh * 8 + 6][n] = v1.z; Bs[kh * 8 + 7][n] = v1.w;
            } else {
                #pragma unroll
                for (int j = 0; j < 8; ++j) {
                    const int k = k0 + kh * 8 + j;
                    float v = 0.0f;
                    if (ng < N && k < K) v = W[(size_t)ng * K + k];
                    Bs[kh * 8 + j][n] = v;
                }
            }
        }
        __syncthreads();
        #pragma unroll
        for (int kk = 0; kk < 16; ++kk) {
            const float4 a0 = *(const float4*)&As[kk][tm * 4];
            const float4 a1 = *(const float4*)&As[kk][tm * 4 + 64];
            const float4 b0 = *(const float4*)&Bs[kk][tn * 4];
            const float4 b1 = *(const float4*)&Bs[kk][tn * 4 + 64];
            const float a[8] = { a0.x, a0.y, a0.z, a0.w, a1.x, a1.y, a1.z, a1.w };
            const float b[8] = { b0.x, b0.y, b0.z, b0.w, b1.x, b1.y, b1.z, b1.w };
            #pragma unroll
            for (int i = 0; i < 8; ++i)
                #pragma unroll
                for (int j = 0; j < 8; ++j)
                    acc[i][j] += a[i] * b[j];
        }
        __syncthreads();
    }
    // ---- epilogue (rows: tm*4+i and 64+tm*4+i; cols: tn*4+j and 64+tn*4+j) ----
    #pragma unroll
    for (int i = 0; i < 8; ++i) {
        const int m = m0 + ((i < 4) ? (tm * 4 + i) : (tm * 4 + 64 + (i - 4)));
        if (CMODE == 0) {
            float r0[4], r1[4];
            #pragma unroll
            for (int j = 0; j < 4; ++j) {
                const int na = n0 + tn * 4 + j;
                float v = acc[i][j] + bias[na];
                if (ACT == 1) v = fast_tanh(v);
                else if (ACT == 2) v = __expf(v);
                r0[j] = v;
                const int nb = n0 + 64 + tn * 4 + j;
                float u = acc[i][j + 4] + bias[nb];
                if (ACT == 1) u = fast_tanh(u);
                else if (ACT == 2) u = __expf(u);
                r1[j] = u;
            }
            *(float4*)&C[(size_t)m * N + n0 + tn * 4]      = make_float4(r0[0], r0[1], r0[2], r0[3]);
            *(float4*)&C[(size_t)m * N + n0 + 64 + tn * 4] = make_float4(r1[0], r1[1], r1[2], r1[3]);
        } else {
            const int bb = m >> 9;
            const int tt = m & 511;
            #pragma unroll
            for (int j = 0; j < 8; ++j) {
                const int n = n0 + ((j < 4) ? (tn * 4 + j) : (64 + tn * 4 + (j - 4)));
                if (n < N) {
                    float v = acc[i][j] + bias[n];
                    if (ACT == 1) v = fast_tanh(v);
                    else if (ACT == 2) v = __expf(v);
                    C[(size_t)bb * (F_DIM * T_DIM) + (size_t)n * T_DIM + tt] = v;
                }
            }
        }
    }
}

#define PIN4(v) asm volatile("" : "+v"((v).x), "+v"((v).y), "+v"((v).z), "+v"((v).w))

// Backward LSTM: one block per batch row b, 512 threads (8 waves).
// Thread (wave w, lane l): h-index j = w*16 + (l&15), K-quarter kq = l>>4.
// Per-thread weights: 4 gates x 32 K-elems = 128 VGPRs, re-PINned at the
// bottom of every t-iteration (loop-carried asm dependence) so the compiler
// cannot re-materialize them inside the loop.
// Cross-kq combine: shfl_xor 16 + 32 (in-wave). Double-buffered LDS h, ONE
// barrier per step. gin layout [B,T,512] (biases folded), g_out [B,T,128].
__global__ __launch_bounds__(512, 2) void lstm_kernel(
    const float* __restrict__ gin,
    const float* __restrict__ W_hh,   // [512,128] row-major
    float* __restrict__ g_out)
{
    __shared__ float hbuf[2][128];
    const int tid  = threadIdx.x;
    const int b    = blockIdx.x;
    const int lane = tid & 63;
    const int w    = tid >> 6;             // wave 0..7
    const int j    = w * 16 + (lane & 15); // h index 0..127
    const int kq   = lane >> 4;            // K-quarter 0..3

    // weights: rows j, j+128, j+256, j+384, float4 cols [kq*8, kq*8+8)
    float4 wi[8], wf[8], wg[8], wo[8];
    {
        const float4* w4 = (const float4*)W_hh;
        const int cb = kq * 8;
        #pragma unroll
        for (int q = 0; q < 8; ++q) {
            wi[q] = w4[(size_t)(j      ) * 32 + cb + q];
            wf[q] = w4[(size_t)(j + 128) * 32 + cb + q];
            wg[q] = w4[(size_t)(j + 256) * 32 + cb + q];
            wo[q] = w4[(size_t)(j + 384) * 32 + cb + q];
        }
        #pragma unroll
        for (int q = 0; q < 8; ++q) { PIN4(wi[q]); PIN4(wf[q]); PIN4(wg[q]); PIN4(wo[q]); }
    }
    if (tid < 128) { hbuf[0][tid] = 0.f; hbuf[1][tid] = 0.f; }
    float c = 0.0f;
    __syncthreads();

    const float* ginb = gin + (size_t)b * T_DIM * G4;
    float gi = ginb[(size_t)(T_DIM - 1) * G4 + j];
    float gf = ginb[(size_t)(T_DIM - 1) * G4 + j + 128];
    float gg = ginb[(size_t)(T_DIM - 1) * G4 + j + 256];
    float go = ginb[(size_t)(T_DIM - 1) * G4 + j + 384];

    int buf = 0;
    for (int t = T_DIM - 1; t >= 0; --t) {
        float ngi = 0.f, ngf = 0.f, ngg = 0.f, ngo = 0.f;
        if (t > 0) {
            const size_t base = (size_t)(t - 1) * G4;
            ngi = ginb[base + j];
            ngf = ginb[base + j + 128];
            ngg = ginb[base + j + 256];
            ngo = ginb[base + j + 384];
        }
        float si = 0.f, sf = 0.f, sg = 0.f, so = 0.f;
        {
            const float4* h4 = (const float4*)&hbuf[buf][kq * 32];
            #pragma unroll
            for (int q = 0; q < 8; ++q) {
                const float4 hv = h4[q];
                si += wi[q].x * hv.x + wi[q].y * hv.y + wi[q].z * hv.z + wi[q].w * hv.w;
                sf += wf[q].x * hv.x + wf[q].y * hv.y + wf[q].z * hv.z + wf[q].w * hv.w;
                sg += wg[q].x * hv.x + wg[q].y * hv.y + wg[q].z * hv.z + wg[q].w * hv.w;
                so += wo[q].x * hv.x + wo[q].y * hv.y + wo[q].z * hv.z + wo[q].w * hv.w;
            }
        }
        si += __shfl_xor(si, 16, 64); si += __shfl_xor(si, 32, 64);
        sf += __shfl_xor(sf, 16, 64); sf += __shfl_xor(sf, 32, 64);
        sg += __shfl_xor(sg, 16, 64); sg += __shfl_xor(sg, 32, 64);
        so += __shfl_xor(so, 16, 64); so += __shfl_xor(so, 32, 64);
        si += gi; sf += gf; sg += gg; so += go;
        c = fast_sig(sf) * c + fast_sig(si) * fast_tanh(sg);
        const float h = fast_sig(so) * fast_tanh(c);
        buf ^= 1;
        if (kq == 0) {
            hbuf[buf][j] = h;
            g_out[((size_t)b * T_DIM + t) * H_DIM + j] = h;
        }
        __syncthreads();
        gi = ngi; gf = ngf; gg = ngg; go = ngo;
        // Loop-carried pin: weights must cross the back-edge in VGPRs.
        #pragma unroll
        for (int q = 0; q < 8; ++q) { PIN4(wi[q]); PIN4(wf[q]); PIN4(wg[q]); PIN4(wo[q]); }
    }
}

// Inference scan: one block (1 wave, 64 lanes) per batch row. All weights in registers.
// g layout [B,T,128], eps layout [T,B,16], z_out layout [B,T,16].
__global__ __launch_bounds__(64, 1) void infer_kernel(
    const float* __restrict__ g,
    const float* __restrict__ eps,
    const float* __restrict__ W_zg0, const float* __restrict__ b_zg0,
    const float* __restrict__ W_zg1, const float* __restrict__ b_zg1,
    const float* __restrict__ W_im,  const float* __restrict__ b_im,
    const float* __restrict__ W_il,  const float* __restrict__ b_il,
    float* __restrict__ z_out)
{
    __shared__ float zbuf[16];
    __shared__ float hzbuf[32];
    __shared__ float h2buf[128];
    const int l = threadIdx.x;
    const int b = blockIdx.x;

    // stage-1 weights: W_zg0 row (l&31), 16 wide
    const int r0 = l & 31;
    float4 wz0[4];
    #pragma unroll
    for (int q = 0; q < 4; ++q) wz0[q] = ((const float4*)W_zg0)[r0 * 4 + q];
    const float bz0 = b_zg0[r0];
    // stage-2 weights: W_zg1 rows l and l+64, 32 wide each
    float4 w1a[8], w1b[8];
    #pragma unroll
    for (int q = 0; q < 8; ++q) {
        w1a[q] = ((const float4*)W_zg1)[l * 8 + q];
        w1b[q] = ((const float4*)W_zg1)[(l + 64) * 8 + q];
    }
    const float bz1a = b_zg1[l], bz1b = b_zg1[l + 64];
    // stage-3 weights: output o=l&31 (o<16: zm row o; else zl row o-16), k half = l>>5
    const int o = l & 31;
    const int half = l >> 5;
    const float* w3p = (o < 16) ? (W_im + o * 128) : (W_il + (o - 16) * 128);
    float4 w3[16];
    #pragma unroll
    for (int q = 0; q < 16; ++q) w3[q] = ((const float4*)(w3p + half * 64))[q];
    const float b3 = (o < 16) ? b_im[o] : b_il[o - 16];

    if (l < 16) zbuf[l] = 0.0f;
    __syncthreads();

    const float* gb = g + (size_t)b * T_DIM * 128;
    float ngl0 = gb[l];
    float ngl1 = gb[64 + l];
    float neps = (l < 16) ? eps[(size_t)b * 16 + l] : 0.0f;
    for (int t = 0; t < T_DIM; ++t) {
        const float gl0 = ngl0, gl1 = ngl1, epsv = neps;
        if (t + 1 < T_DIM) {
            ngl0 = gb[(size_t)(t + 1) * 128 + l];
            ngl1 = gb[(size_t)(t + 1) * 128 + 64 + l];
            neps = (l < 16) ? eps[((size_t)(t + 1) * B_DIM + b) * 16 + l] : 0.0f;
        }
        // stage 1: hz = tanh(W_zg0 @ z + b_zg0), lanes 0..31
        float s1 = bz0;
        {
            const float4* z4 = (const float4*)zbuf;
            #pragma unroll
            for (int q = 0; q < 4; ++q) {
                const float4 zv = z4[q];
                s1 += wz0[q].x * zv.x + wz0[q].y * zv.y + wz0[q].z * zv.z + wz0[q].w * zv.w;
            }
        }
        const float hz = fast_tanh(s1);
        __syncthreads();
        if (l < 32) hzbuf[l] = hz;
        __syncthreads();
        // stage 2: hz2 = tanh(W_zg1 @ hz + b_zg1); g_t = 0.5*(hz2 + g_rnn)
        float s2a = bz1a, s2b = bz1b;
        {
            const float4* hz4 = (const float4*)hzbuf;
            #pragma unroll
            for (int q = 0; q < 8; ++q) {
                const float4 hv = hz4[q];
                s2a += w1a[q].x * hv.x + w1a[q].y * hv.y + w1a[q].z * hv.z + w1a[q].w * hv.w;
                s2b += w1b[q].x * hv.x + w1b[q].y * hv.y + w1b[q].z * hv.z + w1b[q].w * hv.w;
            }
        }
        const float gt0 = 0.5f * (fast_tanh(s2a) + gl0);
        const float gt1 = 0.5f * (fast_tanh(s2b) + gl1);
        __syncthreads();
        h2buf[l]      = gt0;
        h2buf[l + 64] = gt1;
        __syncthreads();
        // stage 3: zm/zl dot-128, split over lane pairs (l, l^32), outputs o=l&31
        float s3 = 0.0f;
        {
            const float4* h24 = (const float4*)(h2buf + half * 64);
            #pragma unroll
            for (int q = 0; q < 16; ++q) {
                const float4 hv = h24[q];
                s3 += w3[q].x * hv.x + w3[q].y * hv.y + w3[q].z * hv.z + w3[q].w * hv.w;
            }
        }
        const float full = s3 + __shfl_xor(s3, 32, 64);
        const float val = full + b3;                 // o<16: zm[o], o>=16: zl[o-16]
        const float other = __shfl_xor(val, 16, 64); // for l<16: zl[l]
        const float znew = val + epsv * __expf(0.5f * other);
        __syncthreads();
        if (l < 16) {
            zbuf[l] = znew;
            z_out[((size_t)b * T_DIM + t) * 16 + l] = znew;
        }
        __syncthreads();
    }
}

extern "C" void kernel_launch(void* const* d_in, const int* in_sizes, int n_in,
                              void* d_out, int out_size, void* d_ws, size_t ws_size,
                              hipStream_t stream)
{
    const float* x     = (const float*)d_in[0];
    const float* eps   = (const float*)d_in[1];
    const float* W_xg  = (const float*)d_in[2];
    const float* b_xg  = (const float*)d_in[3];
    const float* W_ih  = (const float*)d_in[4];
    const float* W_hh  = (const float*)d_in[5];
    const float* b_ih  = (const float*)d_in[6];
    const float* b_hh  = (const float*)d_in[7];
    const float* W_zg0 = (const float*)d_in[8];
    const float* b_zg0 = (const float*)d_in[9];
    const float* W_zg1 = (const float*)d_in[10];
    const float* b_zg1 = (const float*)d_in[11];
    const float* W_im  = (const float*)d_in[12];
    const float* b_im  = (const float*)d_in[13];
    const float* W_il  = (const float*)d_in[14];
    const float* b_il  = (const float*)d_in[15];
    // 16..27: gate/prop/pm/pl weights — dead code (outputs unused by reference return)
    const float* W_zx0 = (const float*)d_in[28];
    const float* b_zx0 = (const float*)d_in[29];
    const float* W_zx1 = (const float*)d_in[30];
    const float* b_zx1 = (const float*)d_in[31];
    const float* W_gy  = (const float*)d_in[32];
    const float* b_gy  = (const float*)d_in[33];
    float* out = (float*)d_out;
    float* ws  = (float*)d_ws;

    // workspace layout (floats)
    float* xg  = ws;                        // 131072*256 = 33,554,432
    float* gin = ws + 33554432ull;          // 131072*512 = 67,108,864
    float* g   = ws + 100663296ull;         // 131072*128 = 16,777,216
    float* z   = ws + 117440512ull;         // 131072*16  =  2,097,152
    float* bc  = ws + 119537664ull;         // 512
    float* hy1 = ws;                        // alias xg (dead after G2)
    float* hy2 = ws + 16777216ull;          // alias xg upper half

    bias_comb_kernel<<<1, 512, 0, stream>>>(b_ih, b_hh, bc);
    // G1: xg = tanh(xs @ W_xg.T + b_xg), m = b*T+t, A = x gather, K=513
    gemm_kernel<1, 1, 0, true><<<dim3(DX / 128, M_ROWS / 128), 256, 0, stream>>>(
        x, W_xg, b_xg, xg, M_ROWS, DX, F_DIM);
    // G2: gin = xg @ W_ih.T + (b_ih + b_hh), K=256, N=512
    gemm_kernel<0, 0, 0, false><<<dim3(G4 / 128, M_ROWS / 128), 256, 0, stream>>>(
        xg, W_ih, bc, gin, M_ROWS, G4, DX);
    // backward LSTM scan -> g
    lstm_kernel<<<B_DIM, 512, 0, stream>>>(gin, W_hh, g);
    // inference scan -> z
    infer_kernel<<<B_DIM, 64, 0, stream>>>(g, eps, W_zg0, b_zg0, W_zg1, b_zg1,
                                           W_im, b_im, W_il, b_il, z);
    // y path
    gemm_kernel<1, 0, 0, false><<<dim3(DZX_D / 128, M_ROWS / 128), 256, 0, stream>>>(
        z, W_zx0, b_zx0, hy1, M_ROWS, DZX_D, Z_DIM);
    gemm_kernel<1, 0, 0, false><<<dim3(DZX_D / 128, M_ROWS / 128), 256, 0, stream>>>(
        hy1, W_zx1, b_zx1, hy2, M_ROWS, DZX_D, DZX_D);
    gemm_kernel<2, 0, 1, true><<<dim3(5, M_ROWS / 128), 256, 0, stream>>>(
        hy2, W_gy, b_gy, out, M_ROWS, F_DIM, DZX_D);
}